// Round 3
// baseline (2535.588 us; speedup 1.0000x reference)
//
#include <hip/hip_runtime.h>

#define VV 32000
#define EE 256
#define HH 512
#define BB 32
#define SS 80
#define TT 80
// decoder rows = B*(T-1) = 2528, padded to 2560 (20 tiles of 128)

typedef __attribute__((ext_vector_type(8))) _Float16 half8;
typedef __attribute__((ext_vector_type(2))) _Float16 half2v;
typedef __attribute__((ext_vector_type(4))) float floatx4;

__device__ __forceinline__ void gload16(const _Float16* g, _Float16* l) {
  // async global->LDS, 16B per lane; LDS dest is wave-uniform base + lane*16
  __builtin_amdgcn_global_load_lds((const __attribute__((address_space(1))) void*)g,
                                   (__attribute__((address_space(3))) void*)l, 16, 0, 0);
}

__device__ __forceinline__ float dot8(half8 a, half8 b, float c) {
  half2v a0 = {a[0],a[1]}, a1 = {a[2],a[3]}, a2 = {a[4],a[5]}, a3 = {a[6],a[7]};
  half2v b0 = {b[0],b[1]}, b1 = {b[2],b[3]}, b2 = {b[4],b[5]}, b3 = {b[6],b[7]};
  c = __builtin_amdgcn_fdot2(a0, b0, c, false);
  c = __builtin_amdgcn_fdot2(a1, b1, c, false);
  c = __builtin_amdgcn_fdot2(a2, b2, c, false);
  c = __builtin_amdgcn_fdot2(a3, b3, c, false);
  return c;
}

__device__ __forceinline__ float sigm(float x) { return 1.f/(1.f + __expf(-x)); }
__device__ __forceinline__ float tanh_f(float x) { return 2.f/(1.f + __expf(-2.f*x)) - 1.f; }

// ---------------- embedding gather (fp32 -> fp16 rows) ----------------
__global__ __launch_bounds__(256) void embed_gather(
    const int* __restrict__ src, const int* __restrict__ tgt,
    const float* __restrict__ emb,
    _Float16* __restrict__ xsrc, _Float16* __restrict__ xdec)
{
  const int r = blockIdx.x;
  const int e = threadIdx.x; // EE == 256
  if (r < 2560) {
    const int tok = src[r];                       // r = b*80+s
    xsrc[(size_t)r*EE + e] = (_Float16)emb[(size_t)tok*EE + e];
  } else {
    const int rr = r - 2560;
    if (rr < 2528) {
      const int b = rr / 79, t = rr - b*79;
      const int tok = tgt[b*TT + t];
      xdec[(size_t)rr*EE + e] = (_Float16)emb[(size_t)tok*EE + e];
    } else {
      xdec[(size_t)rr*EE + e] = (_Float16)0.f;    // pad rows 2528..2559
    }
  }
}

// ---------------- weight fp32 -> fp16 conversion (Wih, out_W) ----------------
__global__ __launch_bounds__(256) void wconv(
    const float* __restrict__ we, const float* __restrict__ wd, const float* __restrict__ ow,
    _Float16* __restrict__ weh, _Float16* __restrict__ wdh, _Float16* __restrict__ owh)
{
  const long n1 = 1536L*256;
  const long total = 2*n1 + (long)VV*1024;
  for (long i = (long)blockIdx.x*256 + threadIdx.x; i < total; i += (long)gridDim.x*256) {
    if (i < n1)           weh[i]        = (_Float16)we[i];
    else if (i < 2*n1)    wdh[i-n1]     = (_Float16)wd[i-n1];
    else                  owh[i-2*n1]   = (_Float16)ow[i-2*n1];
  }
}

// ---------------- Whh fp32 -> fp16 tiled layout -------------------------------
// in:  W[row][k], row = g*512 + col (g = gate 0..2), k = 0..511
// out: tile[((k/8)*1536 + col*3 + g)*8 + k%8]
// so thread `col` reads its 3 gate-vectors for k-chunk c at ONE base + {0,16,32}B.
__global__ __launch_bounds__(256) void whh_conv(
    const float* __restrict__ W, _Float16* __restrict__ out)
{
  const int row = blockIdx.x;          // 0..1535
  const int g = row >> 9, col = row & 511;
  for (int k = threadIdx.x; k < 512; k += 256) {
    out[((size_t)(k>>3)*1536 + col*3 + g)*8 + (k&7)] = (_Float16)W[(size_t)row*512 + k];
  }
}

// ---------------- generic fp16 MFMA GEMM: C(MxN) = A(MxK) * B(NxK)^T + bias ----
// MODE 0: C[row*ldc+col].  MODE 1: seq2seq logits scatter (skip rows>=2528).
template<int MODE>
__global__ __launch_bounds__(256) void mfma_gemm(
    const _Float16* __restrict__ A, int lda,
    const _Float16* __restrict__ Bm, int ldb,
    const float* __restrict__ bias,
    float* __restrict__ Cout, int ldc, int K)
{
  __shared__ _Float16 As[4096];  // 128 x 32
  __shared__ _Float16 Bs[4096];  // 128 x 32
  const int tid = threadIdx.x;
  const int lane = tid & 63;
  const int wv = tid >> 6;
  const int wr = wv >> 1, wc = wv & 1;
  const int mt = blockIdx.y, nt = blockIdx.x;
  floatx4 acc[4][4];
#pragma unroll
  for (int i=0;i<4;++i)
#pragma unroll
    for (int j=0;j<4;++j) acc[i][j] = (floatx4){0.f,0.f,0.f,0.f};
  const int srow = lane >> 2;
  const int scol = (lane & 3) * 8;
  const _Float16* Ab = A + (size_t)(mt*128)*lda;
  const _Float16* Bb = Bm + (size_t)(nt*128)*ldb;
  const int g8 = (lane >> 4) * 8;
  const int lr = lane & 15;
  for (int kb = 0; kb < K; kb += 32) {
    __syncthreads();   // protect LDS from prior iteration's readers
#pragma unroll
    for (int cc = 0; cc < 2; ++cc) {
      const int c = wv*2 + cc;   // 8 chunks of 1KB per 8KB tile
      gload16(Ab + (size_t)(c*16 + srow)*lda + kb + scol, As + c*512);
      gload16(Bb + (size_t)(c*16 + srow)*ldb + kb + scol, Bs + c*512);
    }
    __syncthreads();   // compiler drains vmcnt before barrier
    half8 af[4], bf[4];
#pragma unroll
    for (int i=0;i<4;++i) af[i] = *(const half8*)(As + (wr*64 + i*16 + lr)*32 + g8);
#pragma unroll
    for (int j=0;j<4;++j) bf[j] = *(const half8*)(Bs + (wc*64 + j*16 + lr)*32 + g8);
#pragma unroll
    for (int i=0;i<4;++i)
#pragma unroll
      for (int j=0;j<4;++j)
        acc[i][j] = __builtin_amdgcn_mfma_f32_16x16x32_f16(af[i], bf[j], acc[i][j], 0,0,0);
  }
  const int rm = 4*(lane>>4);  // C/D: col=lane&15, row=4*(lane>>4)+reg (m89-verified)
#pragma unroll
  for (int i=0;i<4;++i) {
#pragma unroll
    for (int r=0;r<4;++r) {
      const int row = mt*128 + wr*64 + i*16 + rm + r;
#pragma unroll
      for (int j=0;j<4;++j) {
        const int col = nt*128 + wc*64 + j*16 + lr;
        const float v = acc[i][j][r] + bias[col];
        if (MODE == 0) {
          Cout[(size_t)row*ldc + col] = v;
        } else {
          if (row < 2528) {
            const int b = row / 79;
            const int t = row - b*79;
            Cout[(size_t)(b*80 + t + 1)*VV + col] = v;  // logits[b, t+1, :]
          }
        }
      }
    }
  }
}

// ---------------- per-batch recurrence: NO cross-WG communication -------------
// 32 WGs (one per batch) x 512 threads (one per h column). h in LDS; Whh fp16
// tiled streams from L2 (same 1.5 MB read by all WGs every step). VALU matvec
// via v_dot2_f32_f16; fp32 h_prev carried in a register.
__global__ __launch_bounds__(512) void seq_batch(
    const _Float16* __restrict__ eWt, const _Float16* __restrict__ dWt,
    const float* __restrict__ ebhh, const float* __restrict__ dbhh,
    const float* __restrict__ giE, const float* __restrict__ giD,
    _Float16* __restrict__ eo, _Float16* __restrict__ comb)
{
  const int b   = blockIdx.x;
  const int t0  = threadIdx.x;        // 0..511: owns h column t0
  const int lane = t0 & 63;
  const int wv   = t0 >> 6;           // 0..7
  __shared__ _Float16 h16s[512];
  __shared__ float sc[SS], aw[SS];

  h16s[t0] = (_Float16)0.f;
  float hp = 0.f;
  const float ebr = ebhh[t0], ebz = ebhh[512+t0], ebn = ebhh[1024+t0];
  const float dbr = dbhh[t0], dbz = dbhh[512+t0], dbn = dbhh[1024+t0];
  __syncthreads();

  // -------- encoder: 80 steps --------
  for (int t = 0; t < SS; ++t) {
    const float* gi = giE + (size_t)(b*SS + t)*1536;
    const float gir = gi[t0], giz = gi[512+t0], gin = gi[1024+t0];
    float ar = 0.f, az = 0.f, an = 0.f;
    const _Float16* wp = eWt + (size_t)t0*24;
#pragma unroll 4
    for (int c = 0; c < 64; ++c) {
      const half8 hv = *(const half8*)&h16s[c*8];        // LDS broadcast
      const half8 w0 = *(const half8*)(wp);
      const half8 w1 = *(const half8*)(wp + 8);
      const half8 w2 = *(const half8*)(wp + 16);
      ar = dot8(w0, hv, ar);
      az = dot8(w1, hv, az);
      an = dot8(w2, hv, an);
      wp += 12288;                                       // next k-chunk (24 KB)
    }
    const float rg = sigm(gir + ar + ebr);
    const float zg = sigm(giz + az + ebz);
    const float ng = tanh_f(gin + rg*(an + ebn));
    const float hn = (1.f - zg)*ng + zg*hp;
    hp = hn;
    __syncthreads();                  // all reads of h16s done
    h16s[t0] = (_Float16)hn;
    eo[((size_t)b*SS + t)*HH + t0] = (_Float16)hn;
    __syncthreads();                  // h16s ready
  }

  // -------- decoder: 79 steps + attention --------
  for (int t = 0; t < TT-1; ++t) {
    const float* gi = giD + (size_t)(b*79 + t)*1536;
    const float gir = gi[t0], giz = gi[512+t0], gin = gi[1024+t0];
    float ar = 0.f, az = 0.f, an = 0.f;
    const _Float16* wp = dWt + (size_t)t0*24;
#pragma unroll 4
    for (int c = 0; c < 64; ++c) {
      const half8 hv = *(const half8*)&h16s[c*8];
      const half8 w0 = *(const half8*)(wp);
      const half8 w1 = *(const half8*)(wp + 8);
      const half8 w2 = *(const half8*)(wp + 16);
      ar = dot8(w0, hv, ar);
      az = dot8(w1, hv, az);
      an = dot8(w2, hv, an);
      wp += 12288;
    }
    const float rg = sigm(gir + ar + dbr);
    const float zg = sigm(giz + az + dbz);
    const float ng = tanh_f(gin + rg*(an + dbn));
    const float hn = (1.f - zg)*ng + zg*hp;
    hp = hn;
    __syncthreads();
    h16s[t0] = (_Float16)hn;
    __syncthreads();

    // scores: 8 waves x 10 rows; full-wave dot over 512
    const _Float16* eob = eo + (size_t)b*SS*HH;
#pragma unroll 2
    for (int i = 0; i < 10; ++i) {
      const int s = wv*10 + i;
      const half8 ev = *(const half8*)&eob[(size_t)s*HH + lane*8];
      const half8 hv = *(const half8*)&h16s[lane*8];
      float p = dot8(ev, hv, 0.f);
#pragma unroll
      for (int o = 32; o; o >>= 1) p += __shfl_xor(p, o);
      if (lane == 0) sc[s] = p;
    }
    __syncthreads();
    if (wv == 0) {                    // softmax over 80 by wave 0
      const float v0 = sc[lane];
      const float v1 = (lane < 16) ? sc[64+lane] : -1e30f;
      float m = fmaxf(v0, v1);
#pragma unroll
      for (int o = 32; o; o >>= 1) m = fmaxf(m, __shfl_xor(m, o));
      const float e0 = __expf(v0 - m);
      const float e1 = (lane < 16) ? __expf(v1 - m) : 0.f;
      float ssum = e0 + e1;
#pragma unroll
      for (int o = 32; o; o >>= 1) ssum += __shfl_xor(ssum, o);
      const float inv = 1.f/ssum;
      aw[lane] = e0*inv;
      if (lane < 16) aw[64+lane] = e1*inv;
    }
    __syncthreads();
    // ctx column t0
    float cx = 0.f;
#pragma unroll 8
    for (int s = 0; s < SS; ++s) cx += aw[s] * (float)eob[(size_t)s*HH + t0];
    _Float16* cr = comb + ((size_t)b*79 + t)*1024;
    cr[t0]       = (_Float16)hn;
    cr[512 + t0] = (_Float16)cx;
    // no trailing sync needed: every next-iter write is behind >=1 barrier
  }
  // zero pad row of combined (2528+b)
  {
    _Float16* cr = comb + (size_t)(2528 + b)*1024;
    cr[t0]       = (_Float16)0.f;
    cr[512 + t0] = (_Float16)0.f;
  }
}

// ---------------- logits[:,0,:] = 0 ----------------
__global__ __launch_bounds__(256) void zero_t0(float* __restrict__ out)
{
  const int i = blockIdx.x*256 + threadIdx.x;
  if (i < BB*VV) {
    const int b = i / VV, v = i - b*VV;
    out[(size_t)(b*TT)*VV + v] = 0.f;
  }
}

extern "C" void kernel_launch(void* const* d_in, const int* in_sizes, int n_in,
                              void* d_out, int out_size, void* d_ws, size_t ws_size,
                              hipStream_t stream) {
  (void)in_sizes; (void)n_in; (void)out_size; (void)ws_size;
  const int*   src  = (const int*)d_in[0];
  const int*   tgt  = (const int*)d_in[1];
  const float* emb  = (const float*)d_in[2];
  const float* eWih = (const float*)d_in[3];
  const float* eWhh = (const float*)d_in[4];
  const float* ebih = (const float*)d_in[5];
  const float* ebhh = (const float*)d_in[6];
  const float* dWih = (const float*)d_in[7];
  const float* dWhh = (const float*)d_in[8];
  const float* dbih = (const float*)d_in[9];
  const float* dbhh = (const float*)d_in[10];
  const float* outW = (const float*)d_in[11];
  const float* outb = (const float*)d_in[12];
  float* out = (float*)d_out;

  char* p = (char*)d_ws;
  auto alloc = [&](size_t n){ char* r = p; p += (n + 255) & ~(size_t)255; return r; };
  _Float16* xsrc = (_Float16*)alloc((size_t)2560*256*2);
  _Float16* xdec = (_Float16*)alloc((size_t)2560*256*2);
  _Float16* wEh  = (_Float16*)alloc((size_t)1536*256*2);
  _Float16* wDh  = (_Float16*)alloc((size_t)1536*256*2);
  _Float16* oWh  = (_Float16*)alloc((size_t)VV*1024*2);
  _Float16* wTe  = (_Float16*)alloc((size_t)1536*512*2);   // tiled enc Whh fp16
  _Float16* wTd  = (_Float16*)alloc((size_t)1536*512*2);   // tiled dec Whh fp16
  float*    giE  = (float*)alloc((size_t)2560*1536*4);
  float*    giD  = (float*)alloc((size_t)2560*1536*4);
  _Float16* eo   = (_Float16*)alloc((size_t)BB*SS*HH*2);
  _Float16* comb = (_Float16*)alloc((size_t)2560*1024*2);

  embed_gather<<<5120, 256, 0, stream>>>(src, tgt, emb, xsrc, xdec);
  wconv<<<2048, 256, 0, stream>>>(eWih, dWih, outW, wEh, wDh, oWh);
  whh_conv<<<1536, 256, 0, stream>>>(eWhh, wTe);
  whh_conv<<<1536, 256, 0, stream>>>(dWhh, wTd);
  // gi = x @ Wih^T + bih for all timesteps at once
  mfma_gemm<0><<<dim3(12,20), 256, 0, stream>>>(xsrc, 256, wEh, 256, ebih, giE, 1536, 256);
  mfma_gemm<0><<<dim3(12,20), 256, 0, stream>>>(xdec, 256, wDh, 256, dbih, giD, 1536, 256);
  seq_batch<<<32, 512, 0, stream>>>(wTe, wTd, ebhh, dbhh, giE, giD, eo, comb);
  zero_t0<<<4000, 256, 0, stream>>>(out);
  // logits = combined @ out_W^T + out_b, scattered to [b, t+1, :]
  mfma_gemm<1><<<dim3(250,20), 256, 0, stream>>>(comb, 1024, oWh, 1024, outb, out, 0, 1024);
}

// Round 4
// 2108.882 us; speedup vs baseline: 1.2023x; 1.2023x over previous
//
#include <hip/hip_runtime.h>

#define VV 32000
#define EE 256
#define HH 512
#define BB 32
#define SS 80
#define TT 80
// decoder rows = B*(T-1) = 2528, padded to 2560 (20 tiles of 128)

typedef __attribute__((ext_vector_type(8))) _Float16 half8;
typedef __attribute__((ext_vector_type(4))) _Float16 half4;
typedef __attribute__((ext_vector_type(4))) float floatx4;
typedef unsigned long long u64;

__device__ __forceinline__ void gload16(const _Float16* g, _Float16* l) {
  __builtin_amdgcn_global_load_lds((const __attribute__((address_space(1))) void*)g,
                                   (__attribute__((address_space(3))) void*)l, 16, 0, 0);
}

__device__ __forceinline__ u64 aload(const u64* p) {
  return __hip_atomic_load(p, __ATOMIC_RELAXED, __HIP_MEMORY_SCOPE_AGENT);
}
__device__ __forceinline__ void astore(u64* p, u64 v) {
  __hip_atomic_store(p, v, __ATOMIC_RELAXED, __HIP_MEMORY_SCOPE_AGENT);
}

__device__ __forceinline__ float dot8(half8 a, half8 b, float c) {
  typedef __attribute__((ext_vector_type(2))) _Float16 half2v;
  half2v a0 = {a[0],a[1]}, a1 = {a[2],a[3]}, a2 = {a[4],a[5]}, a3 = {a[6],a[7]};
  half2v b0 = {b[0],b[1]}, b1 = {b[2],b[3]}, b2 = {b[4],b[5]}, b3 = {b[6],b[7]};
  c = __builtin_amdgcn_fdot2(a0, b0, c, false);
  c = __builtin_amdgcn_fdot2(a1, b1, c, false);
  c = __builtin_amdgcn_fdot2(a2, b2, c, false);
  c = __builtin_amdgcn_fdot2(a3, b3, c, false);
  return c;
}

__device__ __forceinline__ float sigm(float x) { return 1.f/(1.f + __expf(-x)); }
__device__ __forceinline__ float tanh_f(float x) { return 2.f/(1.f + __expf(-2.f*x)) - 1.f; }

// ---------------- embedding gather (fp32 -> fp16 rows) ----------------
__global__ __launch_bounds__(256) void embed_gather(
    const int* __restrict__ src, const int* __restrict__ tgt,
    const float* __restrict__ emb,
    _Float16* __restrict__ xsrc, _Float16* __restrict__ xdec)
{
  const int r = blockIdx.x;
  const int e = threadIdx.x; // EE == 256
  if (r < 2560) {
    const int tok = src[r];
    xsrc[(size_t)r*EE + e] = (_Float16)emb[(size_t)tok*EE + e];
  } else {
    const int rr = r - 2560;
    if (rr < 2528) {
      const int b = rr / 79, t = rr - b*79;
      const int tok = tgt[b*TT + t];
      xdec[(size_t)rr*EE + e] = (_Float16)emb[(size_t)tok*EE + e];
    } else {
      xdec[(size_t)rr*EE + e] = (_Float16)0.f;
    }
  }
}

// ---------------- weight fp32 -> fp16 conversion (Wih, out_W) ----------------
__global__ __launch_bounds__(256) void wconv(
    const float* __restrict__ we, const float* __restrict__ wd, const float* __restrict__ ow,
    _Float16* __restrict__ weh, _Float16* __restrict__ wdh, _Float16* __restrict__ owh)
{
  const long n1 = 1536L*256;
  const long total = 2*n1 + (long)VV*1024;
  for (long i = (long)blockIdx.x*256 + threadIdx.x; i < total; i += (long)gridDim.x*256) {
    if (i < n1)           weh[i]        = (_Float16)we[i];
    else if (i < 2*n1)    wdh[i-n1]     = (_Float16)wd[i-n1];
    else                  owh[i-2*n1]   = (_Float16)ow[i-2*n1];
  }
}

// ---------------- generic fp16 MFMA GEMM: C(MxN) = A(MxK) * B(NxK)^T + bias ----
template<int MODE>
__global__ __launch_bounds__(256) void mfma_gemm(
    const _Float16* __restrict__ A, int lda,
    const _Float16* __restrict__ Bm, int ldb,
    const float* __restrict__ bias,
    float* __restrict__ Cout, int ldc, int K)
{
  __shared__ _Float16 As[4096];  // 128 x 32
  __shared__ _Float16 Bs[4096];  // 128 x 32
  const int tid = threadIdx.x;
  const int lane = tid & 63;
  const int wv = tid >> 6;
  const int wr = wv >> 1, wc = wv & 1;
  const int mt = blockIdx.y, nt = blockIdx.x;
  floatx4 acc[4][4];
#pragma unroll
  for (int i=0;i<4;++i)
#pragma unroll
    for (int j=0;j<4;++j) acc[i][j] = (floatx4){0.f,0.f,0.f,0.f};
  const int srow = lane >> 2;
  const int scol = (lane & 3) * 8;
  const _Float16* Ab = A + (size_t)(mt*128)*lda;
  const _Float16* Bb = Bm + (size_t)(nt*128)*ldb;
  const int g8 = (lane >> 4) * 8;
  const int lr = lane & 15;
  for (int kb = 0; kb < K; kb += 32) {
    __syncthreads();
#pragma unroll
    for (int cc = 0; cc < 2; ++cc) {
      const int c = wv*2 + cc;
      gload16(Ab + (size_t)(c*16 + srow)*lda + kb + scol, As + c*512);
      gload16(Bb + (size_t)(c*16 + srow)*ldb + kb + scol, Bs + c*512);
    }
    __syncthreads();
    half8 af[4], bf[4];
#pragma unroll
    for (int i=0;i<4;++i) af[i] = *(const half8*)(As + (wr*64 + i*16 + lr)*32 + g8);
#pragma unroll
    for (int j=0;j<4;++j) bf[j] = *(const half8*)(Bs + (wc*64 + j*16 + lr)*32 + g8);
#pragma unroll
    for (int i=0;i<4;++i)
#pragma unroll
      for (int j=0;j<4;++j)
        acc[i][j] = __builtin_amdgcn_mfma_f32_16x16x32_f16(af[i], bf[j], acc[i][j], 0,0,0);
  }
  const int rm = 4*(lane>>4);
#pragma unroll
  for (int i=0;i<4;++i) {
#pragma unroll
    for (int r=0;r<4;++r) {
      const int row = mt*128 + wr*64 + i*16 + rm + r;
#pragma unroll
      for (int j=0;j<4;++j) {
        const int col = nt*128 + wc*64 + j*16 + lr;
        const float v = acc[i][j][r] + bias[col];
        if (MODE == 0) {
          Cout[(size_t)row*ldc + col] = v;
        } else {
          if (row < 2528) {
            const int b = row / 79;
            const int t = row - b*79;
            Cout[(size_t)(b*80 + t + 1)*VV + col] = v;
          }
        }
      }
    }
  }
}

// ---------------- fused recurrence: weight-stationary, LLC h-exchange --------
// 32 WGs x 128 threads. WG w owns h cols [w*16,w*16+16); Whh slice (48x512
// fp16) resident in LDS for the whole kernel. Per step: burst-load all h
// B-fragments from LLC (sc1), 48 MFMAs, gates, sc1 store of h slice, fence-
// free grid barrier (relaxed add + poll; data coherence via sc1 accesses).
// Encoder h rows for batch w are stashed in LDS (eo_l, 80KB) so decoder
// attention is LDS-only.
#define SEQ_SMEM ((48*520 + 80*512 + 512)*2 + 160*4)
__global__ __launch_bounds__(128) void seq_fused(
    const float* __restrict__ eWhh, const float* __restrict__ dWhh,
    const float* __restrict__ ebhh, const float* __restrict__ dbhh,
    const float* __restrict__ giE, const float* __restrict__ giD,
    _Float16* __restrict__ h16,    // ping-pong 2 x 32 x 512 fp16
    _Float16* __restrict__ comb,
    unsigned* __restrict__ bar)
{
  extern __shared__ char smem[];
  _Float16* whh  = (_Float16*)smem;        // [48][520] fp16 (padded rows)
  _Float16* eo_l = whh + 48*520;           // [80][512] fp16
  _Float16* hsh  = eo_l + 80*512;          // [512]
  float* sc = (float*)(hsh + 512);         // [80]
  float* aw = sc + 80;                     // [80]

  const int w = blockIdx.x;
  const int tid = threadIdx.x;
  const int lane = tid & 63;
  const int wv = tid >> 6;            // 0..1 batch group
  const int lr = lane & 15;
  const int l4 = lane >> 4;           // 0..3
  const int b  = wv*16 + lr;          // batch this thread covers (gates/B-frag)
  const int jc = w*16 + 4*l4;         // global h-col base (4 wide)
  unsigned bphase = 0;

  auto loadW = [&](const float* W){
    for (int i = tid; i < 48*512; i += 128) {
      const int r = i >> 9, k = i & 511;
      whh[r*520 + k] = (_Float16)W[((size_t)(r>>4)*512 + w*16 + (r&15))*512 + k];
    }
  };
  auto gbar = [&](){
    asm volatile("s_waitcnt vmcnt(0)" ::: "memory");  // drain own sc1 stores
    __syncthreads();
    if (tid == 0) {
      __hip_atomic_fetch_add(bar, 1u, __ATOMIC_RELAXED, __HIP_MEMORY_SCOPE_AGENT);
      const unsigned tg = (++bphase)*32u;
      while (__hip_atomic_load(bar, __ATOMIC_RELAXED, __HIP_MEMORY_SCOPE_AGENT) < tg)
        __builtin_amdgcn_s_sleep(1);
      asm volatile("" ::: "memory");
    }
    __syncthreads();
  };

  // bias registers (fp32, 4 cols each gate)
  const floatx4 ebr = *(const floatx4*)&ebhh[jc];
  const floatx4 ebz = *(const floatx4*)&ebhh[HH + jc];
  const floatx4 ebn = *(const floatx4*)&ebhh[2*HH + jc];
  const floatx4 dbr = *(const floatx4*)&dbhh[jc];
  const floatx4 dbz = *(const floatx4*)&dbhh[HH + jc];
  const floatx4 dbn = *(const floatx4*)&dbhh[2*HH + jc];

  float hp[4] = {0.f, 0.f, 0.f, 0.f};   // own fp32 h_prev (batch b, cols jc..jc+3)

  auto gru = [&](const float* girow, floatx4 bR, floatx4 bZ, floatx4 bN, int p){
    const floatx4 gr = *(const floatx4*)(girow);
    const floatx4 gz = *(const floatx4*)(girow + HH);
    const floatx4 gn = *(const floatx4*)(girow + 2*HH);
    // burst-load h B-fragments: 32 independent sc1 u64 loads
    const u64* hb = (const u64*)(h16 + (size_t)p*BB*HH) + b*128 + l4*2;
    u64 hq[32];
#pragma unroll
    for (int kt = 0; kt < 16; ++kt) {
      hq[2*kt]   = aload(hb + kt*8);
      hq[2*kt+1] = aload(hb + kt*8 + 1);
    }
    floatx4 a0 = (floatx4){0.f,0.f,0.f,0.f}, a1 = a0, a2 = a0;
#pragma unroll
    for (int kt = 0; kt < 16; ++kt) {
      union { u64 q[2]; half8 v; } hu;
      hu.q[0] = hq[2*kt]; hu.q[1] = hq[2*kt+1];
      const int ko = kt*32 + l4*8;
      const half8 x0 = *(const half8*)&whh[(     lr)*520 + ko];
      const half8 x1 = *(const half8*)&whh[(16 + lr)*520 + ko];
      const half8 x2 = *(const half8*)&whh[(32 + lr)*520 + ko];
      a0 = __builtin_amdgcn_mfma_f32_16x16x32_f16(x0, hu.v, a0, 0,0,0);
      a1 = __builtin_amdgcn_mfma_f32_16x16x32_f16(x1, hu.v, a1, 0,0,0);
      a2 = __builtin_amdgcn_mfma_f32_16x16x32_f16(x2, hu.v, a2, 0,0,0);
    }
    union { u64 q; _Float16 h[4]; } hw;
#pragma unroll
    for (int r = 0; r < 4; ++r) {
      const float rg = sigm(gr[r] + a0[r] + bR[r]);
      const float zg = sigm(gz[r] + a1[r] + bZ[r]);
      const float ng = tanh_f(gn[r] + rg*(a2[r] + bN[r]));
      const float hn = (1.f - zg)*ng + zg*hp[r];
      hp[r] = hn;
      hw.h[r] = (_Float16)hn;
    }
    astore((u64*)(h16 + (size_t)(1-p)*BB*HH) + b*128 + w*4 + l4, hw.q);
  };

  // init ping buffer 0 (4096 u64 words over 32 WGs x 128 threads)
  astore((u64*)h16 + w*128 + tid, 0ull);
  loadW(eWhh);
  gbar();

  // -------- encoder: 80 steps; stash h[w] rows into LDS eo_l --------
  for (int t = 0; t < SS; ++t) {
    const int p = t & 1;
    if (t > 0) {   // stash step t-1's h[w] (in read buffer p)
      const u64 q = aload((const u64*)(h16 + (size_t)p*BB*HH) + w*128 + tid);
      *(u64*)&eo_l[(t-1)*512 + tid*4] = q;
    }
    gru(giE + (size_t)(b*SS + t)*1536 + jc, ebr, ebz, ebn, p);
    gbar();
  }
  {  // stash row 79 (final encoder h, in buffer 0)
    const u64 q = aload((const u64*)h16 + w*128 + tid);
    *(u64*)&eo_l[79*512 + tid*4] = q;
  }

  // -------- decoder: 79 steps + attention (all LDS) --------
  loadW(dWhh);
  __syncthreads();
  for (int t = 0; t < TT-1; ++t) {
    const int p = t & 1;
    gru(giD + (size_t)(b*79 + t)*1536 + jc, dbr, dbz, dbn, p);
    gbar();
    // stash new h[w] (buffer 1-p) into hsh
    {
      const u64 q = aload((const u64*)(h16 + (size_t)(1-p)*BB*HH) + w*128 + tid);
      *(u64*)&hsh[tid*4] = q;
    }
    __syncthreads();
    // scores: 2 waves x 40, full-wave dot over 512
    const half8 hf = *(const half8*)&hsh[lane*8];
#pragma unroll 4
    for (int i = 0; i < 40; ++i) {
      const int s = wv*40 + i;
      const half8 ev = *(const half8*)&eo_l[s*512 + lane*8];
      float pt = dot8(ev, hf, 0.f);
#pragma unroll
      for (int o = 32; o; o >>= 1) pt += __shfl_xor(pt, o);
      if (lane == 0) sc[s] = pt;
    }
    __syncthreads();
    if (wv == 0) {   // softmax over 80 (wave 0)
      const float v0 = sc[lane];
      const float v1 = (lane < 16) ? sc[64+lane] : -1e30f;
      float m = fmaxf(v0, v1);
#pragma unroll
      for (int o = 32; o; o >>= 1) m = fmaxf(m, __shfl_xor(m, o));
      const float e0 = __expf(v0 - m);
      const float e1 = (lane < 16) ? __expf(v1 - m) : 0.f;
      float ssum = e0 + e1;
#pragma unroll
      for (int o = 32; o; o >>= 1) ssum += __shfl_xor(ssum, o);
      const float inv = 1.f/ssum;
      aw[lane] = e0*inv;
      if (lane < 16) aw[64+lane] = e1*inv;
    }
    __syncthreads();
    // ctx cols tid*4..+4 from LDS
    float c0=0.f, c1=0.f, c2=0.f, c3=0.f;
#pragma unroll 8
    for (int s = 0; s < SS; ++s) {
      const float a = aw[s];
      const half4 hv = *(const half4*)&eo_l[s*512 + tid*4];
      c0 += a*(float)hv[0]; c1 += a*(float)hv[1];
      c2 += a*(float)hv[2]; c3 += a*(float)hv[3];
    }
    _Float16* cr = comb + ((size_t)w*79 + t)*1024;
    *(u64*)&cr[tid*4] = *(const u64*)&hsh[tid*4];
    union { u64 q; _Float16 h[4]; } cu;
    cu.h[0]=(_Float16)c0; cu.h[1]=(_Float16)c1; cu.h[2]=(_Float16)c2; cu.h[3]=(_Float16)c3;
    *(u64*)&cr[512 + tid*4] = cu.q;
  }
  // zero pad row of combined (2528+w)
  {
    _Float16* cr = comb + (size_t)(2528 + w)*1024;
    *(u64*)&cr[tid*8]     = 0ull;
    *(u64*)&cr[tid*8 + 4] = 0ull;
  }
}

// ---------------- logits[:,0,:] = 0 ----------------
__global__ __launch_bounds__(256) void zero_t0(float* __restrict__ out)
{
  const int i = blockIdx.x*256 + threadIdx.x;
  if (i < BB*VV) {
    const int b = i / VV, v = i - b*VV;
    out[(size_t)(b*TT)*VV + v] = 0.f;
  }
}

extern "C" void kernel_launch(void* const* d_in, const int* in_sizes, int n_in,
                              void* d_out, int out_size, void* d_ws, size_t ws_size,
                              hipStream_t stream) {
  (void)in_sizes; (void)n_in; (void)out_size; (void)ws_size;
  const int*   src  = (const int*)d_in[0];
  const int*   tgt  = (const int*)d_in[1];
  const float* emb  = (const float*)d_in[2];
  const float* eWih = (const float*)d_in[3];
  const float* eWhh = (const float*)d_in[4];
  const float* ebih = (const float*)d_in[5];
  const float* ebhh = (const float*)d_in[6];
  const float* dWih = (const float*)d_in[7];
  const float* dWhh = (const float*)d_in[8];
  const float* dbih = (const float*)d_in[9];
  const float* dbhh = (const float*)d_in[10];
  const float* outW = (const float*)d_in[11];
  const float* outb = (const float*)d_in[12];
  float* out = (float*)d_out;

  char* p = (char*)d_ws;
  auto alloc = [&](size_t n){ char* r = p; p += (n + 255) & ~(size_t)255; return r; };
  _Float16* xsrc = (_Float16*)alloc((size_t)2560*256*2);
  _Float16* xdec = (_Float16*)alloc((size_t)2560*256*2);
  _Float16* wEh  = (_Float16*)alloc((size_t)1536*256*2);
  _Float16* wDh  = (_Float16*)alloc((size_t)1536*256*2);
  _Float16* oWh  = (_Float16*)alloc((size_t)VV*1024*2);
  float*    giE  = (float*)alloc((size_t)2560*1536*4);
  float*    giD  = (float*)alloc((size_t)2560*1536*4);
  _Float16* h16  = (_Float16*)alloc((size_t)2*BB*HH*2);
  _Float16* comb = (_Float16*)alloc((size_t)2560*1024*2);
  unsigned* bar  = (unsigned*)alloc(256);

  hipMemsetAsync(bar, 0, 256, stream);
  embed_gather<<<5120, 256, 0, stream>>>(src, tgt, emb, xsrc, xdec);
  wconv<<<2048, 256, 0, stream>>>(eWih, dWih, outW, wEh, wDh, oWh);
  mfma_gemm<0><<<dim3(12,20), 256, 0, stream>>>(xsrc, 256, wEh, 256, ebih, giE, 1536, 256);
  mfma_gemm<0><<<dim3(12,20), 256, 0, stream>>>(xdec, 256, wDh, 256, dbih, giD, 1536, 256);
  hipFuncSetAttribute((const void*)seq_fused,
                      hipFuncAttributeMaxDynamicSharedMemorySize, SEQ_SMEM);
  seq_fused<<<32, 128, SEQ_SMEM, stream>>>(eWhh, dWhh, ebhh, dbhh, giE, giD,
                                           h16, comb, bar);
  zero_t0<<<4000, 256, 0, stream>>>(out);
  mfma_gemm<1><<<dim3(250,20), 256, 0, stream>>>(comb, 1024, oWh, 1024, outb, out, 0, 1024);
}

// Round 5
// 1950.520 us; speedup vs baseline: 1.3000x; 1.0812x over previous
//
#include <hip/hip_runtime.h>

#define VV 32000
#define EE 256
#define HH 512
#define BB 32
#define SS 80
#define TT 80
// decoder rows = B*(T-1) = 2528, padded to 2560 (20 tiles of 128)

typedef __attribute__((ext_vector_type(8))) _Float16 half8;
typedef __attribute__((ext_vector_type(4))) _Float16 half4;
typedef __attribute__((ext_vector_type(4))) float floatx4;
typedef unsigned long long u64;

__device__ __forceinline__ void gload16(const _Float16* g, _Float16* l) {
  __builtin_amdgcn_global_load_lds((const __attribute__((address_space(1))) void*)g,
                                   (__attribute__((address_space(3))) void*)l, 16, 0, 0);
}

__device__ __forceinline__ u64 aload(const u64* p) {
  return __hip_atomic_load(p, __ATOMIC_RELAXED, __HIP_MEMORY_SCOPE_AGENT);
}
__device__ __forceinline__ void astore(u64* p, u64 v) {
  __hip_atomic_store(p, v, __ATOMIC_RELAXED, __HIP_MEMORY_SCOPE_AGENT);
}

__device__ __forceinline__ float dot8(half8 a, half8 b, float c) {
  typedef __attribute__((ext_vector_type(2))) _Float16 half2v;
  half2v a0 = {a[0],a[1]}, a1 = {a[2],a[3]}, a2 = {a[4],a[5]}, a3 = {a[6],a[7]};
  half2v b0 = {b[0],b[1]}, b1 = {b[2],b[3]}, b2 = {b[4],b[5]}, b3 = {b[6],b[7]};
  c = __builtin_amdgcn_fdot2(a0, b0, c, false);
  c = __builtin_amdgcn_fdot2(a1, b1, c, false);
  c = __builtin_amdgcn_fdot2(a2, b2, c, false);
  c = __builtin_amdgcn_fdot2(a3, b3, c, false);
  return c;
}

__device__ __forceinline__ float sigm(float x) { return 1.f/(1.f + __expf(-x)); }
__device__ __forceinline__ float tanh_f(float x) { return 2.f/(1.f + __expf(-2.f*x)) - 1.f; }

// ---------------- embedding gather (fp32 -> fp16 rows) ----------------
__global__ __launch_bounds__(256) void embed_gather(
    const int* __restrict__ src, const int* __restrict__ tgt,
    const float* __restrict__ emb,
    _Float16* __restrict__ xsrc, _Float16* __restrict__ xdec)
{
  const int r = blockIdx.x;
  const int e = threadIdx.x; // EE == 256
  if (r < 2560) {
    const int tok = src[r];
    xsrc[(size_t)r*EE + e] = (_Float16)emb[(size_t)tok*EE + e];
  } else {
    const int rr = r - 2560;
    if (rr < 2528) {
      const int b = rr / 79, t = rr - b*79;
      const int tok = tgt[b*TT + t];
      xdec[(size_t)rr*EE + e] = (_Float16)emb[(size_t)tok*EE + e];
    } else {
      xdec[(size_t)rr*EE + e] = (_Float16)0.f;
    }
  }
}

// ---------------- weight fp32 -> fp16 conversion (Wih, out_W) ----------------
__global__ __launch_bounds__(256) void wconv(
    const float* __restrict__ we, const float* __restrict__ wd, const float* __restrict__ ow,
    _Float16* __restrict__ weh, _Float16* __restrict__ wdh, _Float16* __restrict__ owh)
{
  const long n1 = 1536L*256;
  const long total = 2*n1 + (long)VV*1024;
  for (long i = (long)blockIdx.x*256 + threadIdx.x; i < total; i += (long)gridDim.x*256) {
    if (i < n1)           weh[i]        = (_Float16)we[i];
    else if (i < 2*n1)    wdh[i-n1]     = (_Float16)wd[i-n1];
    else                  owh[i-2*n1]   = (_Float16)ow[i-2*n1];
  }
}

// ---------------- generic fp16 MFMA GEMM: C(MxN) = A(MxK) * B(NxK)^T + bias ----
template<int MODE>
__global__ __launch_bounds__(256) void mfma_gemm(
    const _Float16* __restrict__ A, int lda,
    const _Float16* __restrict__ Bm, int ldb,
    const float* __restrict__ bias,
    float* __restrict__ Cout, int ldc, int K)
{
  __shared__ _Float16 As[4096];  // 128 x 32
  __shared__ _Float16 Bs[4096];  // 128 x 32
  const int tid = threadIdx.x;
  const int lane = tid & 63;
  const int wv = tid >> 6;
  const int wr = wv >> 1, wc = wv & 1;
  const int mt = blockIdx.y, nt = blockIdx.x;
  floatx4 acc[4][4];
#pragma unroll
  for (int i=0;i<4;++i)
#pragma unroll
    for (int j=0;j<4;++j) acc[i][j] = (floatx4){0.f,0.f,0.f,0.f};
  const int srow = lane >> 2;
  const int scol = (lane & 3) * 8;
  const _Float16* Ab = A + (size_t)(mt*128)*lda;
  const _Float16* Bb = Bm + (size_t)(nt*128)*ldb;
  const int g8 = (lane >> 4) * 8;
  const int lr = lane & 15;
  for (int kb = 0; kb < K; kb += 32) {
    __syncthreads();
#pragma unroll
    for (int cc = 0; cc < 2; ++cc) {
      const int c = wv*2 + cc;
      gload16(Ab + (size_t)(c*16 + srow)*lda + kb + scol, As + c*512);
      gload16(Bb + (size_t)(c*16 + srow)*ldb + kb + scol, Bs + c*512);
    }
    __syncthreads();
    half8 af[4], bf[4];
#pragma unroll
    for (int i=0;i<4;++i) af[i] = *(const half8*)(As + (wr*64 + i*16 + lr)*32 + g8);
#pragma unroll
    for (int j=0;j<4;++j) bf[j] = *(const half8*)(Bs + (wc*64 + j*16 + lr)*32 + g8);
#pragma unroll
    for (int i=0;i<4;++i)
#pragma unroll
      for (int j=0;j<4;++j)
        acc[i][j] = __builtin_amdgcn_mfma_f32_16x16x32_f16(af[i], bf[j], acc[i][j], 0,0,0);
  }
  const int rm = 4*(lane>>4);
#pragma unroll
  for (int i=0;i<4;++i) {
#pragma unroll
    for (int r=0;r<4;++r) {
      const int row = mt*128 + wr*64 + i*16 + rm + r;
#pragma unroll
      for (int j=0;j<4;++j) {
        const int col = nt*128 + wc*64 + j*16 + lr;
        const float v = acc[i][j][r] + bias[col];
        if (MODE == 0) {
          Cout[(size_t)row*ldc + col] = v;
        } else {
          if (row < 2528) {
            const int b = row / 79;
            const int t = row - b*79;
            Cout[(size_t)(b*80 + t + 1)*VV + col] = v;
          }
        }
      }
    }
  }
}

// ---------------- fused recurrence: weight-stationary, distributed flags ----
// 32 WGs x 128 threads. WG w owns h cols [w*16,w*16+16); Whh slice (48x512
// fp16) resident in LDS. Sync protocol (NO central barrier, NO RMW):
//   producer: sc1 data stores -> s_waitcnt vmcnt(0) -> sc1 store of monotone
//             step number to its OWN flag cacheline flags[buf][w].
//   consumer: 32 lanes poll the 32 producers' flags (independent cachelines),
//             then burst-load h. Ping-pong depth 2 is safe: completing step
//             t's writes implies step t's reads are done (data dependence),
//             and a WG enters step t+1 only after all flags show step t.
// Decoder attention is DEFERRED one step: at iter t we stash h(t-1) (same
// buffer the gru burst reads), publish h(t) first, then run attention(t-1)
// so no other WG ever waits on our attention.
#define SEQ_SMEM ((48*520 + 80*512 + 512)*2 + 160*4)
__global__ __launch_bounds__(128) void seq_fused(
    const float* __restrict__ eWhh, const float* __restrict__ dWhh,
    const float* __restrict__ ebhh, const float* __restrict__ dbhh,
    const float* __restrict__ giE, const float* __restrict__ giD,
    _Float16* __restrict__ h16,    // ping-pong 2 x 32 x 512 fp16
    _Float16* __restrict__ comb,
    unsigned* __restrict__ flags)  // [2][32] monotone step counters, 128B apart
{
  extern __shared__ char smem[];
  _Float16* whh  = (_Float16*)smem;        // [48][520] fp16 (padded rows)
  _Float16* eo_l = whh + 48*520;           // [80][512] fp16
  _Float16* hsh  = eo_l + 80*512;          // [512]
  float* sc = (float*)(hsh + 512);         // [80]
  float* aw = sc + 80;                     // [80]

  const int w = blockIdx.x;
  const int tid = threadIdx.x;
  const int lane = tid & 63;
  const int wv = tid >> 6;            // 0..1 batch group
  const int lr = lane & 15;
  const int l4 = lane >> 4;           // 0..3
  const int b  = wv*16 + lr;          // batch this thread covers (gates/B-frag)
  const int jc = w*16 + 4*l4;         // global h-col base (4 wide)

  auto loadW = [&](const float* W){
    for (int i = tid; i < 48*512; i += 128) {
      const int r = i >> 9, k = i & 511;
      whh[r*520 + k] = (_Float16)W[((size_t)(r>>4)*512 + w*16 + (r&15))*512 + k];
    }
  };
  auto wait_flags = [&](int buf, unsigned tgt){
    if (tid < 32) {
      while (__hip_atomic_load(&flags[(buf*32 + tid)*32], __ATOMIC_RELAXED,
                               __HIP_MEMORY_SCOPE_AGENT) < tgt)
        __builtin_amdgcn_s_sleep(1);
    }
    __syncthreads();
  };
  auto publish = [&](int buf, unsigned val){
    asm volatile("s_waitcnt vmcnt(0)" ::: "memory");   // all sc1 data stores done
    __syncthreads();
    if (tid == 0)
      __hip_atomic_store(&flags[(buf*32 + w)*32], val, __ATOMIC_RELAXED,
                         __HIP_MEMORY_SCOPE_AGENT);
  };

  // bias registers (fp32, 4 cols each gate)
  const floatx4 ebr = *(const floatx4*)&ebhh[jc];
  const floatx4 ebz = *(const floatx4*)&ebhh[HH + jc];
  const floatx4 ebn = *(const floatx4*)&ebhh[2*HH + jc];
  const floatx4 dbr = *(const floatx4*)&dbhh[jc];
  const floatx4 dbz = *(const floatx4*)&dbhh[HH + jc];
  const floatx4 dbn = *(const floatx4*)&dbhh[2*HH + jc];

  float hp[4] = {0.f, 0.f, 0.f, 0.f};   // own fp32 h_prev (batch b, cols jc..jc+3)

  auto gru = [&](const float* girow, floatx4 bR, floatx4 bZ, floatx4 bN, int p){
    const floatx4 gr = *(const floatx4*)(girow);
    const floatx4 gz = *(const floatx4*)(girow + HH);
    const floatx4 gn = *(const floatx4*)(girow + 2*HH);
    // burst-load h B-fragments: 32 independent sc1 u64 loads (pipelined)
    const u64* hb = (const u64*)(h16 + (size_t)p*BB*HH) + b*128 + l4*2;
    u64 hq[32];
#pragma unroll
    for (int kt = 0; kt < 16; ++kt) {
      hq[2*kt]   = aload(hb + kt*8);
      hq[2*kt+1] = aload(hb + kt*8 + 1);
    }
    floatx4 a0 = (floatx4){0.f,0.f,0.f,0.f}, a1 = a0, a2 = a0;
#pragma unroll
    for (int kt = 0; kt < 16; ++kt) {
      union { u64 q[2]; half8 v; } hu;
      hu.q[0] = hq[2*kt]; hu.q[1] = hq[2*kt+1];
      const int ko = kt*32 + l4*8;
      const half8 x0 = *(const half8*)&whh[(     lr)*520 + ko];
      const half8 x1 = *(const half8*)&whh[(16 + lr)*520 + ko];
      const half8 x2 = *(const half8*)&whh[(32 + lr)*520 + ko];
      a0 = __builtin_amdgcn_mfma_f32_16x16x32_f16(x0, hu.v, a0, 0,0,0);
      a1 = __builtin_amdgcn_mfma_f32_16x16x32_f16(x1, hu.v, a1, 0,0,0);
      a2 = __builtin_amdgcn_mfma_f32_16x16x32_f16(x2, hu.v, a2, 0,0,0);
    }
    union { u64 q; _Float16 h[4]; } hw;
#pragma unroll
    for (int r = 0; r < 4; ++r) {
      const float rg = sigm(gr[r] + a0[r] + bR[r]);
      const float zg = sigm(gz[r] + a1[r] + bZ[r]);
      const float ng = tanh_f(gn[r] + rg*(a2[r] + bN[r]));
      const float hn = (1.f - zg)*ng + zg*hp[r];
      hp[r] = hn;
      hw.h[r] = (_Float16)hn;
    }
    astore((u64*)(h16 + (size_t)(1-p)*BB*HH) + b*128 + w*4 + l4, hw.q);
  };

  auto attention = [&](int trow){
    // scores: 2 waves x 40, full-wave dot over 512 (hsh holds h(trow))
    const half8 hf = *(const half8*)&hsh[lane*8];
#pragma unroll 4
    for (int i = 0; i < 40; ++i) {
      const int s = wv*40 + i;
      const half8 ev = *(const half8*)&eo_l[s*512 + lane*8];
      float pt = dot8(ev, hf, 0.f);
#pragma unroll
      for (int o = 32; o; o >>= 1) pt += __shfl_xor(pt, o);
      if (lane == 0) sc[s] = pt;
    }
    __syncthreads();
    if (wv == 0) {   // softmax over 80 (wave 0)
      const float v0 = sc[lane];
      const float v1 = (lane < 16) ? sc[64+lane] : -1e30f;
      float m = fmaxf(v0, v1);
#pragma unroll
      for (int o = 32; o; o >>= 1) m = fmaxf(m, __shfl_xor(m, o));
      const float e0 = __expf(v0 - m);
      const float e1 = (lane < 16) ? __expf(v1 - m) : 0.f;
      float ssum = e0 + e1;
#pragma unroll
      for (int o = 32; o; o >>= 1) ssum += __shfl_xor(ssum, o);
      const float inv = 1.f/ssum;
      aw[lane] = e0*inv;
      if (lane < 16) aw[64+lane] = e1*inv;
    }
    __syncthreads();
    float c0=0.f, c1=0.f, c2=0.f, c3=0.f;
#pragma unroll 8
    for (int s = 0; s < SS; ++s) {
      const float a = aw[s];
      const half4 hv = *(const half4*)&eo_l[s*512 + tid*4];
      c0 += a*(float)hv[0]; c1 += a*(float)hv[1];
      c2 += a*(float)hv[2]; c3 += a*(float)hv[3];
    }
    _Float16* cr = comb + ((size_t)w*79 + trow)*1024;
    *(u64*)&cr[tid*4] = *(const u64*)&hsh[tid*4];
    union { u64 q; _Float16 h[4]; } cu;
    cu.h[0]=(_Float16)c0; cu.h[1]=(_Float16)c1; cu.h[2]=(_Float16)c2; cu.h[3]=(_Float16)c3;
    *(u64*)&cr[512 + tid*4] = cu.q;
  };

  // init ping buffer 0 (4096 u64 words over 32 WGs x 128 threads)
  astore((u64*)h16 + w*128 + tid, 0ull);
  loadW(eWhh);
  publish(0, 1);

  // -------- encoder: global iters k = 0..79 --------
  for (int k = 0; k < SS; ++k) {
    const int p = k & 1;
    wait_flags(p, (unsigned)(k+1));
    if (k > 0) {   // stash h(k-1) (= current read buffer, batch w) into eo_l
      const u64 q = aload((const u64*)(h16 + (size_t)p*BB*HH) + w*128 + tid);
      *(u64*)&eo_l[(k-1)*512 + tid*4] = q;
    }
    gru(giE + (size_t)(b*SS + k)*1536 + jc, ebr, ebz, ebn, p);
    publish(1-p, (unsigned)(k+2));
  }

  // -------- decoder: global iters k = 80..158 (t = k-80) --------
  __syncthreads();     // everyone done with enc whh MFMAs (publish barrier passed)
  loadW(dWhh);
  __syncthreads();
  for (int t = 0; t < TT-1; ++t) {
    const int k = 80 + t;
    const int p = k & 1;
    wait_flags(p, (unsigned)(k+1));
    // stash full h from read buffer: t==0 -> enc h(79) completes eo_l;
    // t>0 -> h(dec t-1) for deferred attention
    const u64 q = aload((const u64*)(h16 + (size_t)p*BB*HH) + w*128 + tid);
    if (t == 0) *(u64*)&eo_l[79*512 + tid*4] = q;
    else        *(u64*)&hsh[tid*4] = q;
    gru(giD + (size_t)(b*79 + t)*1536 + jc, dbr, dbz, dbn, p);
    publish(1-p, (unsigned)(k+2));
    if (t > 0) { __syncthreads(); attention(t-1); }
  }
  // final: attention(78) on h(78) (buffer 1, written at k=158 with flag 160)
  wait_flags(1, 160u);
  {
    const u64 q = aload((const u64*)(h16 + (size_t)1*BB*HH) + w*128 + tid);
    *(u64*)&hsh[tid*4] = q;
  }
  __syncthreads();
  attention(TT-2);

  // zero pad row of combined (2528+w)
  {
    _Float16* cr = comb + (size_t)(2528 + w)*1024;
    *(u64*)&cr[tid*8]     = 0ull;
    *(u64*)&cr[tid*8 + 4] = 0ull;
  }
}

// ---------------- logits[:,0,:] = 0 ----------------
__global__ __launch_bounds__(256) void zero_t0(float* __restrict__ out)
{
  const int i = blockIdx.x*256 + threadIdx.x;
  if (i < BB*VV) {
    const int b = i / VV, v = i - b*VV;
    out[(size_t)(b*TT)*VV + v] = 0.f;
  }
}

extern "C" void kernel_launch(void* const* d_in, const int* in_sizes, int n_in,
                              void* d_out, int out_size, void* d_ws, size_t ws_size,
                              hipStream_t stream) {
  (void)in_sizes; (void)n_in; (void)out_size; (void)ws_size;
  const int*   src  = (const int*)d_in[0];
  const int*   tgt  = (const int*)d_in[1];
  const float* emb  = (const float*)d_in[2];
  const float* eWih = (const float*)d_in[3];
  const float* eWhh = (const float*)d_in[4];
  const float* ebih = (const float*)d_in[5];
  const float* ebhh = (const float*)d_in[6];
  const float* dWih = (const float*)d_in[7];
  const float* dWhh = (const float*)d_in[8];
  const float* dbih = (const float*)d_in[9];
  const float* dbhh = (const float*)d_in[10];
  const float* outW = (const float*)d_in[11];
  const float* outb = (const float*)d_in[12];
  float* out = (float*)d_out;

  char* p = (char*)d_ws;
  auto alloc = [&](size_t n){ char* r = p; p += (n + 255) & ~(size_t)255; return r; };
  _Float16* xsrc = (_Float16*)alloc((size_t)2560*256*2);
  _Float16* xdec = (_Float16*)alloc((size_t)2560*256*2);
  _Float16* wEh  = (_Float16*)alloc((size_t)1536*256*2);
  _Float16* wDh  = (_Float16*)alloc((size_t)1536*256*2);
  _Float16* oWh  = (_Float16*)alloc((size_t)VV*1024*2);
  float*    giE  = (float*)alloc((size_t)2560*1536*4);
  float*    giD  = (float*)alloc((size_t)2560*1536*4);
  _Float16* h16  = (_Float16*)alloc((size_t)2*BB*HH*2);
  _Float16* comb = (_Float16*)alloc((size_t)2560*1024*2);
  unsigned* flags= (unsigned*)alloc(2*32*128);

  hipMemsetAsync(flags, 0, 2*32*128, stream);
  embed_gather<<<5120, 256, 0, stream>>>(src, tgt, emb, xsrc, xdec);
  wconv<<<2048, 256, 0, stream>>>(eWih, dWih, outW, wEh, wDh, oWh);
  mfma_gemm<0><<<dim3(12,20), 256, 0, stream>>>(xsrc, 256, wEh, 256, ebih, giE, 1536, 256);
  mfma_gemm<0><<<dim3(12,20), 256, 0, stream>>>(xdec, 256, wDh, 256, dbih, giD, 1536, 256);
  hipFuncSetAttribute((const void*)seq_fused,
                      hipFuncAttributeMaxDynamicSharedMemorySize, SEQ_SMEM);
  seq_fused<<<32, 128, SEQ_SMEM, stream>>>(eWhh, dWhh, ebhh, dbhh, giE, giD,
                                           h16, comb, flags);
  zero_t0<<<4000, 256, 0, stream>>>(out);
  mfma_gemm<1><<<dim3(250,20), 256, 0, stream>>>(comb, 1024, oWh, 1024, outb, out, 0, 1024);
}